// Round 8
// baseline (538.271 us; speedup 1.0000x reference)
//
#include <hip/hip_runtime.h>
#include <math.h>

#define BATCH 4
#define CIN   1024
#define CB    256
#define HH    64
#define WW    64
#define PP    4096          // HH*WW
#define EPSV  1e-5f

using shortx8 = __attribute__((ext_vector_type(8))) short;
using floatx4 = __attribute__((ext_vector_type(4))) float;
using intx4   = __attribute__((ext_vector_type(4))) int;

static __device__ inline unsigned short f2bf(float f) {
    unsigned int u = __float_as_uint(f);
    u += 0x7fffu + ((u >> 16) & 1u);      // RNE
    return (unsigned short)(u >> 16);
}
static __device__ inline float bf2f(unsigned short s) {
    return __uint_as_float(((unsigned int)s) << 16);
}

// ---------------------------------------------------------------------------
// bf16 MFMA GEMM (conv1 / conv3). Unchanged from R4 (proven).
// ---------------------------------------------------------------------------
__global__ __launch_bounds__(256)
void gemm_bf16(const unsigned short* __restrict__ A,
               const unsigned short* __restrict__ BTg,
               float* __restrict__ Cg, int M, int N, int K) {
    const int b = blockIdx.z;
    const unsigned short* BT = BTg + (size_t)b * N * K;
    float* C = Cg + (size_t)b * M * N;
    const int m0 = blockIdx.y * 128;
    const int n0 = blockIdx.x * 128;
    const int tid = threadIdx.x;
    const int lane = tid & 63;
    const int wid = tid >> 6;
    const int l15 = lane & 15;
    const int quad = lane >> 4;

    __shared__ __align__(16) unsigned short As[128 * 40];
    __shared__ __align__(16) unsigned short Bs[128 * 40];

    floatx4 acc[2][8];
#pragma unroll
    for (int i = 0; i < 2; i++)
#pragma unroll
        for (int j = 0; j < 8; j++) acc[i][j] = (floatx4){0.f, 0.f, 0.f, 0.f};

    const int row = tid >> 1;
    const int half = tid & 1;

    for (int k0 = 0; k0 < K; k0 += 32) {
        const unsigned short* ga = A + (size_t)(m0 + row) * K + k0 + half * 16;
        const unsigned short* gb = BT + (size_t)(n0 + row) * K + k0 + half * 16;
        float4 a0 = *(const float4*)ga;
        float4 a1 = *(const float4*)(ga + 8);
        float4 b0 = *(const float4*)gb;
        float4 b1 = *(const float4*)(gb + 8);
        __syncthreads();
        *(float4*)((char*)As + row * 80 + half * 32) = a0;
        *(float4*)((char*)As + row * 80 + half * 32 + 16) = a1;
        *(float4*)((char*)Bs + row * 80 + half * 32) = b0;
        *(float4*)((char*)Bs + row * 80 + half * 32 + 16) = b1;
        __syncthreads();
        shortx8 af[2], bf[8];
#pragma unroll
        for (int i = 0; i < 2; i++)
            af[i] = *(const shortx8*)((const char*)As +
                    (wid * 32 + 16 * i + l15) * 80 + quad * 16);
#pragma unroll
        for (int j = 0; j < 8; j++)
            bf[j] = *(const shortx8*)((const char*)Bs +
                    (16 * j + l15) * 80 + quad * 16);
#pragma unroll
        for (int i = 0; i < 2; i++)
#pragma unroll
            for (int j = 0; j < 8; j++)
                acc[i][j] = __builtin_amdgcn_mfma_f32_16x16x32_bf16(
                    af[i], bf[j], acc[i][j], 0, 0, 0);
    }

#pragma unroll
    for (int i = 0; i < 2; i++) {
#pragma unroll
        for (int r = 0; r < 4; r++) {
            int m = m0 + wid * 32 + 16 * i + quad * 4 + r;
            float* dst = C + (size_t)m * N + n0 + l15;
#pragma unroll
            for (int j = 0; j < 8; j++)
                dst[16 * j] = acc[i][j][r];
        }
    }
}

// ---------------------------------------------------------------------------
// Tiled transpose + fp32->bf16: src [b][C][P] -> dst [b][P][C]
// ---------------------------------------------------------------------------
__global__ __launch_bounds__(256)
void transp_bf16(const float* __restrict__ src, unsigned short* __restrict__ dst,
                 int C, int P) {
    const int p0 = blockIdx.x * 64;
    const int c0 = blockIdx.y * 64;
    const int b = blockIdx.z;
    __shared__ unsigned short t[64][72];
    const float* s = src + ((size_t)b * C + c0) * P + p0;
    for (int e = threadIdx.x; e < 4096; e += 256) {
        int r = e >> 6, col = e & 63;
        t[r][col] = f2bf(s[(size_t)r * P + col]);
    }
    __syncthreads();
    unsigned short* d = dst + ((size_t)b * P + p0) * C + c0;
    for (int u = threadIdx.x; u < 512; u += 256) {
        int pr = u >> 3, c8 = (u & 7) * 8;
        ushort4 v0, v1;
        v0.x = t[c8 + 0][pr]; v0.y = t[c8 + 1][pr];
        v0.z = t[c8 + 2][pr]; v0.w = t[c8 + 3][pr];
        v1.x = t[c8 + 4][pr]; v1.y = t[c8 + 5][pr];
        v1.z = t[c8 + 6][pr]; v1.w = t[c8 + 7][pr];
        *(ushort4*)&d[(size_t)pr * C + c8] = v0;
        *(ushort4*)&d[(size_t)pr * C + c8 + 4] = v1;
    }
}

// ---------------------------------------------------------------------------
// GN2 apply + ReLU + transpose-convert: out2 fp32 [b][256][P] -> bf16 [b][P][256]
// ---------------------------------------------------------------------------
__global__ __launch_bounds__(256)
void gn2t(const float* __restrict__ src, const float2* __restrict__ st,
          const float* __restrict__ sc, const float* __restrict__ bi,
          unsigned short* __restrict__ dst) {
    const int p0 = blockIdx.x * 64;
    const int c0 = blockIdx.y * 64;
    const int b = blockIdx.z;
    __shared__ unsigned short t[64][72];
    const float* s = src + ((size_t)b * CB + c0) * PP + p0;
    for (int e = threadIdx.x; e < 4096; e += 256) {
        int r = e >> 6, col = e & 63;
        int c = c0 + r;
        float2 m = st[b * 32 + (c >> 3)];       // Cpg = 8
        float a = m.y * sc[c];
        float bb = bi[c] - m.x * a;
        t[r][col] = f2bf(fmaxf(s[(size_t)r * PP + col] * a + bb, 0.f));
    }
    __syncthreads();
    unsigned short* d = dst + ((size_t)b * PP + p0) * CB + c0;
    for (int u = threadIdx.x; u < 512; u += 256) {
        int pr = u >> 3, c8 = (u & 7) * 8;
        ushort4 v0, v1;
        v0.x = t[c8 + 0][pr]; v0.y = t[c8 + 1][pr];
        v0.z = t[c8 + 2][pr]; v0.w = t[c8 + 3][pr];
        v1.x = t[c8 + 4][pr]; v1.y = t[c8 + 5][pr];
        v1.z = t[c8 + 6][pr]; v1.w = t[c8 + 7][pr];
        *(ushort4*)&d[(size_t)pr * CB + c8] = v0;
        *(ushort4*)&d[(size_t)pr * CB + c8 + 4] = v1;
    }
}

// ---------------------------------------------------------------------------
__global__ __launch_bounds__(256)
void cvt_bf16(const float* __restrict__ s, unsigned short* __restrict__ d, int n) {
    int i = blockIdx.x * 256 + threadIdx.x;
    if (i < n) d[i] = f2bf(s[i]);
}

// ---------------------------------------------------------------------------
__global__ __launch_bounds__(256)
void gn_stats(const float* __restrict__ src, float2* __restrict__ stats,
              int C, int Cpg) {
    int bg = blockIdx.x;
    int b = bg >> 5, g = bg & 31;
    const float* base = src + ((size_t)b * C + (size_t)g * Cpg) * PP;
    int cnt = Cpg * PP;
    float s = 0.f, ss = 0.f;
    const float4* p4 = (const float4*)base;
    int n4 = cnt >> 2;
    for (int i = threadIdx.x; i < n4; i += 256) {
        float4 v = p4[i];
        s += v.x + v.y + v.z + v.w;
        ss += v.x * v.x + v.y * v.y + v.z * v.z + v.w * v.w;
    }
    for (int off = 32; off > 0; off >>= 1) {
        s += __shfl_down(s, off, 64);
        ss += __shfl_down(ss, off, 64);
    }
    __shared__ float rs[4], rss[4];
    int lane = threadIdx.x & 63, wid = threadIdx.x >> 6;
    if (lane == 0) { rs[wid] = s; rss[wid] = ss; }
    __syncthreads();
    if (threadIdx.x == 0) {
        float S = rs[0] + rs[1] + rs[2] + rs[3];
        float SS = rss[0] + rss[1] + rss[2] + rss[3];
        float mean = S / (float)cnt;
        float var = SS / (float)cnt - mean * mean;
        stats[bg] = make_float2(mean, rsqrtf(var + EPSV));
    }
}

// ---------------------------------------------------------------------------
// GN1 apply + ReLU, fp32 in -> bf16 out (bfA). C=256, Cpg=8 hardcoded.
// ---------------------------------------------------------------------------
__global__ __launch_bounds__(256)
void gn1_apply_bf(const float* __restrict__ src, const float2* __restrict__ stats,
                  const float* __restrict__ sc, const float* __restrict__ bi,
                  unsigned short* __restrict__ dst) {
    long i = (long)blockIdx.x * 256 + threadIdx.x;
    long total4 = ((long)BATCH * CB * PP) >> 2;
    if (i >= total4) return;
    long e = i << 2;
    int c = (int)((e >> 12) & 255);
    int b = (int)(e >> 20);
    float2 st = stats[b * 32 + (c >> 3)];
    float a = st.y * sc[c];
    float bb = bi[c] - st.x * a;
    float4 v = ((const float4*)src)[i];
    ushort4 o;
    o.x = f2bf(fmaxf(v.x * a + bb, 0.f));
    o.y = f2bf(fmaxf(v.y * a + bb, 0.f));
    o.z = f2bf(fmaxf(v.z * a + bb, 0.f));
    o.w = f2bf(fmaxf(v.w * a + bb, 0.f));
    ((ushort4*)dst)[i] = o;
}

// ---------------------------------------------------------------------------
// bfB[m] = bfA[m+1] (flat shift; boundary dwords never used by gathers).
// ---------------------------------------------------------------------------
__global__ __launch_bounds__(256)
void mk_shift(const unsigned short* __restrict__ a, unsigned short* __restrict__ bsh) {
    int t = blockIdx.x * 256 + threadIdx.x;      // 4194304 threads, 4 shorts each
    uint2 d01 = ((const uint2*)a)[t];
    unsigned int d2 = ((const unsigned int*)a)[2 * t + 2];
    unsigned int w0 = (d01.x >> 16) | (d01.y << 16);
    unsigned int w1 = (d01.y >> 16) | (d2 << 16);
    ((uint2*)bsh)[t] = make_uint2(w0, w1);
}

// ---------------------------------------------------------------------------
__global__ __launch_bounds__(256)
void om_init(float* __restrict__ om, const float* __restrict__ boff) {
    int t = blockIdx.x * 256 + threadIdx.x;
    if (t < BATCH * 27 * PP) {
        int r = (t >> 12) % 27;
        om[t] = boff[r];
    }
}

// ---------------------------------------------------------------------------
// 3x3 offset conv. R8: strips for 8 channels staged per round (4 rounds,
// 8 barriers total) instead of per-channel staging (64 barriers) — removes
// the exposed per-channel load latency chain. Reads bf16 bfA.
// LDS: Aall 48 KB + strip 12 KB = 60 KB (< 64 KB static cap).
// ---------------------------------------------------------------------------
__global__ __launch_bounds__(256)
void conv_off_k(const unsigned short* __restrict__ o1bf, const float* __restrict__ w_off,
                float* __restrict__ om) {
    const int y0 = blockIdx.x * 4;
    const int c0 = blockIdx.y * 32;
    const int b = blockIdx.z;
    const int tid = threadIdx.x;
    const int tx = tid & 63, ty = tid >> 6;

    __shared__ __align__(16) float Aall[32 * 384];   // [c][m(32)][k(12)] 48 KB
    __shared__ float strip[8 * 384];                 // [c][6*64] 12 KB

    for (int e = tid; e < 32 * 384; e += 256) {
        int c = e / 384;
        int rk = e % 384;
        int r = rk / 12, k = rk % 12;
        float v = 0.f;
        if (r < 27 && k < 9) v = w_off[((size_t)r * CB + (c0 + c)) * 9 + k];
        Aall[e] = v;
    }

    float acc[8][4];
#pragma unroll
    for (int i = 0; i < 8; i++)
#pragma unroll
        for (int j = 0; j < 4; j++) acc[i][j] = 0.f;

    for (int cg = 0; cg < 4; cg++) {
        __syncthreads();   // prev compute done reading strip (covers Aall 1st time)
        for (int e = tid; e < 8 * 384; e += 256) {
            int c = e / 384, rk = e % 384;
            int r = rk >> 6, col = rk & 63;
            int gy = y0 + r - 1;
            strip[e] = (gy >= 0 && gy < 64)
                ? bf2f(o1bf[(((size_t)b * CB + c0 + cg * 8 + c) << 12) + (gy << 6) + col])
                : 0.f;
        }
        __syncthreads();
        for (int c = 0; c < 8; c++) {
            float v[6][3];
#pragma unroll
            for (int r = 0; r < 6; r++)
#pragma unroll
                for (int d = 0; d < 3; d++) {
                    int col = tx + d - 1;
                    v[r][d] = (col >= 0 && col < 64) ? strip[c * 384 + r * 64 + col] : 0.f;
                }
            const float* Ac = &Aall[(cg * 8 + c) * 384];
#pragma unroll
            for (int i = 0; i < 8; i++) {
                int m = ty + 4 * i;
                float4 w0 = *(const float4*)(Ac + m * 12);
                float4 w1v = *(const float4*)(Ac + m * 12 + 4);
                float w8 = Ac[m * 12 + 8];
                float wk[9] = {w0.x, w0.y, w0.z, w0.w, w1v.x, w1v.y, w1v.z, w1v.w, w8};
#pragma unroll
                for (int kk = 0; kk < 9; kk++) {
                    int dy = kk / 3, dx = kk % 3;
#pragma unroll
                    for (int j = 0; j < 4; j++)
                        acc[i][j] += wk[kk] * v[j + dy][dx];
                }
            }
        }
    }
#pragma unroll
    for (int i = 0; i < 8; i++) {
        int m = ty + 4 * i;
        if (m < 27) {
#pragma unroll
            for (int j = 0; j < 4; j++) {
                int p = ((y0 + j) << 6) + tx;
                atomicAdd(&om[((size_t)b * 27 + m) * PP + p], acc[i][j]);
            }
        }
    }
}

// ---------------------------------------------------------------------------
// w2 fp32 [o][c][tap] -> bf16, K reordered: w2bf[o][tap*256 + c]
// ---------------------------------------------------------------------------
__global__ __launch_bounds__(256)
void w2conv(const float* __restrict__ w2, unsigned short* __restrict__ w2bf) {
    int t = blockIdx.x * 256 + threadIdx.x;
    if (t >= 256 * 2304) return;
    int o = t / 2304;
    int r = t - o * 2304;
    int tap = r >> 8, c = r & 255;
    w2bf[t] = f2bf(w2[((size_t)o * 256 + c) * 9 + tap]);
}

// ---------------------------------------------------------------------------
// Deformable einsum, bf16 MFMA. R8: BN=16 -> grid 1024 = 4 blocks/CU (wave
// cap) for more cross-block latency overlap. Dual-aligned gather (bfA/bfB),
// cc-outer/tap-inner, proven R6/R7 skeleton — no register prefetch.
// ---------------------------------------------------------------------------
__global__ __launch_bounds__(512)
void gemm2_mfma(const unsigned short* __restrict__ bfA,
                const unsigned short* __restrict__ bfB,
                const unsigned short* __restrict__ w2bf,
                const float* __restrict__ om, float* __restrict__ out2) {
    const int p0 = blockIdx.x * 16;
    const int b = blockIdx.z;
    const int tid = threadIdx.x;
    const int lane = tid & 63;
    const int wid = tid >> 6;          // 0..7
    const int l15 = lane & 15;
    const int quad = lane >> 4;        // 0..3

    __shared__ __align__(16) unsigned short As[256 * 40];  // 20.0 KB
    __shared__ __align__(16) unsigned short Bs[16 * 40];   //  1.25 KB
    __shared__ __align__(16) float swL[9 * 16 * 4];        //  2.25 KB
    __shared__ __align__(16) int   siL[9 * 16 * 2];        //  1.125 KB

    // inline samp_prep with pair-swizzled weights (16 pixels x 9 taps)
    const float* ob = om + (size_t)b * 27 * PP;
    for (int e = tid; e < 144; e += 512) {
        int k = e >> 4, p = e & 15;
        int pg = p0 + p;
        float offx = ob[(size_t)k * PP + pg];
        float offy = ob[(size_t)(9 + k) * PP + pg];
        float ms = 1.f / (1.f + expf(-ob[(size_t)(18 + k) * PP + pg]));
        int y = pg >> 6, x = pg & 63;
        float py = (float)(y + k / 3 - 1) + offy;
        float px = (float)(x + (k % 3) - 1) + offx;
        float y0f = floorf(py), x0f = floorf(px);
        float wy1 = py - y0f, wx1 = px - x0f;
        int iy0 = (int)y0f, ix0 = (int)x0f;
        int iy1 = iy0 + 1;
        float wy0v = (iy0 >= 0 && iy0 < 64) ? (1.f - wy1) * ms : 0.f;
        float wy1v = (iy1 >= 0 && iy1 < 64) ? wy1 * ms : 0.f;
        int cy0 = min(max(iy0, 0), 63), cy1 = min(max(iy1, 0), 63);
        float xa, xb; int q;
        if (ix0 >= 0 && ix0 <= 62)      { q = ix0; xa = 1.f - wx1; xb = wx1;       }
        else if (ix0 == -1)             { q = 0;   xa = wx1;       xb = 0.f;       }
        else if (ix0 == 63)             { q = 62;  xa = 0.f;       xb = 1.f - wx1; }
        else                            { q = 0;   xa = 0.f;       xb = 0.f;       }
        swL[e * 4 + 0] = wy0v * xa;
        swL[e * 4 + 1] = wy0v * xb;
        swL[e * 4 + 2] = wy1v * xa;
        swL[e * 4 + 3] = wy1v * xb;
        siL[e * 2 + 0] = (cy0 << 6) + q;
        siL[e * 2 + 1] = (cy1 << 6) + q;
    }

    floatx4 acc[2];
#pragma unroll
    for (int i = 0; i < 2; i++) acc[i] = (floatx4){0.f, 0.f, 0.f, 0.f};

    const int bp = tid & 15;           // pixel within tile
    const int cq = tid >> 4;           // 0..31, 1 channel each
    const int so = tid >> 1;           // A-stage row 0..255
    const int sh = tid & 1;            // A-stage half
    const size_t chbase = ((size_t)b * CB) << 12;

    __syncthreads();   // tables ready

    const int mbase = wid * 32;

    for (int cc = 0; cc < 8; cc++) {
        const int c0 = cc * 32;
        for (int tap = 0; tap < 9; tap++) {
            // A stage: w2bf[o][tap*256 + c0 .. c0+32)
            const unsigned short* gsrc =
                w2bf + (size_t)so * 2304 + tap * 256 + c0 + sh * 16;
            float4 v0 = *(const float4*)gsrc;
            float4 v1 = *(const float4*)(gsrc + 8);
            // B build: 1 channel for pixel bp, 2 aligned dwords
            floatx4 wv = *(const floatx4*)&swL[(tap * 16 + bp) * 4];
            int i0 = siL[(tap * 16 + bp) * 2 + 0];
            int i1 = siL[(tap * 16 + bp) * 2 + 1];
            const unsigned short* bs0 = (i0 & 1) ? bfB : bfA;
            size_t co = chbase + ((size_t)(c0 + cq) << 12);
            unsigned int d0 = *(const unsigned int*)(bs0 + co + (i0 & ~1));
            unsigned int d1 = *(const unsigned int*)(bs0 + co + (i1 & ~1));
            float acv = wv[0] * __uint_as_float(d0 << 16)
                      + wv[1] * __uint_as_float(d0 & 0xffff0000u)
                      + wv[2] * __uint_as_float(d1 << 16)
                      + wv[3] * __uint_as_float(d1 & 0xffff0000u);
            unsigned short bvv = f2bf(acv);
            *(float4*)((char*)As + so * 80 + sh * 32) = v0;
            *(float4*)((char*)As + so * 80 + sh * 32 + 16) = v1;
            *((unsigned short*)((char*)Bs + bp * 80 + cq * 2)) = bvv;
            __syncthreads();
            shortx8 af[2], bfr;
#pragma unroll
            for (int i = 0; i < 2; i++)
                af[i] = *(const shortx8*)((const char*)As +
                        (mbase + 16 * i + l15) * 80 + quad * 16);
            bfr = *(const shortx8*)((const char*)Bs + l15 * 80 + quad * 16);
#pragma unroll
            for (int i = 0; i < 2; i++)
                acc[i] = __builtin_amdgcn_mfma_f32_16x16x32_bf16(
                    af[i], bfr, acc[i], 0, 0, 0);
            __syncthreads();
        }
    }

    // epilogue: D col = lane&15, row = quad*4+reg
#pragma unroll
    for (int i = 0; i < 2; i++) {
#pragma unroll
        for (int r = 0; r < 4; r++) {
            int row = mbase + 16 * i + quad * 4 + r;
            out2[chbase + ((size_t)row << 12) + p0 + l15] = acc[i][r];
        }
    }
}

// ---------------------------------------------------------------------------
// Final: relu(gn3(d_out)*sc+bi + x) in place.
// ---------------------------------------------------------------------------
__global__ __launch_bounds__(256)
void final_k(float* __restrict__ dout, const float* __restrict__ x,
             const float2* __restrict__ stats, const float* __restrict__ sc,
             const float* __restrict__ bi) {
    long i = (long)blockIdx.x * 256 + threadIdx.x;
    long total4 = ((long)BATCH * CIN * PP) >> 2;
    if (i >= total4) return;
    long e = i << 2;
    int c = (int)((e >> 12) & 1023);
    int b = (int)(e >> 22);
    float2 st = stats[b * 32 + (c >> 5)];
    float a = st.y * sc[c];
    float bb = bi[c] - st.x * a;
    float4 v = ((float4*)dout)[i];
    float4 xv = ((const float4*)x)[i];
    v.x = fmaxf(v.x * a + bb + xv.x, 0.f);
    v.y = fmaxf(v.y * a + bb + xv.y, 0.f);
    v.z = fmaxf(v.z * a + bb + xv.z, 0.f);
    v.w = fmaxf(v.w * a + bb + xv.w, 0.f);
    ((float4*)dout)[i] = v;
}

// ---------------------------------------------------------------------------
// Workspace layout identical to R7 (50.9 MB, verified).
// ---------------------------------------------------------------------------
extern "C" void kernel_launch(void* const* d_in, const int* in_sizes, int n_in,
                              void* d_out, int out_size, void* d_ws, size_t ws_size,
                              hipStream_t stream) {
    const float* x   = (const float*)d_in[0];
    const float* w1  = (const float*)d_in[1];
    const float* g1s = (const float*)d_in[2];
    const float* g1b = (const float*)d_in[3];
    const float* wof = (const float*)d_in[4];
    const float* bof = (const float*)d_in[5];
    const float* w2  = (const float*)d_in[6];
    const float* g2s = (const float*)d_in[7];
    const float* g2b = (const float*)d_in[8];
    const float* w3  = (const float*)d_in[9];
    const float* g3s = (const float*)d_in[10];
    const float* g3b = (const float*)d_in[11];
    float* out = (float*)d_out;

    float* ws = (float*)d_ws;
    unsigned short* w1bf   = (unsigned short*)(ws + 0);
    float*          out1r  = ws + 131072;               // conv1 raw out
    float*          out2   = ws + 131072;               // aliases out1r (dead)
    unsigned short* xbfT   = (unsigned short*)(ws + 4325376);
    unsigned short* bfA    = (unsigned short*)(ws + 4325376);
    unsigned short* bfB    = (unsigned short*)(ws + 6422528);
    float*          om     = ws + 8519680;
    unsigned short* w2bf   = (unsigned short*)(ws + 8962048);
    unsigned short* out2bT = (unsigned short*)(ws + 4325376); // aliases bfA (dead)
    unsigned short* w3bf   = (unsigned short*)(ws + 11354112);
    float2* st1 = (float2*)(ws + 11485184);
    float2* st2 = st1 + 128;
    float2* st3 = st2 + 128;

    // x [b][1024][4096] -> xbfT [b][4096][1024] bf16
    transp_bf16<<<dim3(64, 16, 4), 256, 0, stream>>>(x, xbfT, 1024, 4096);
    cvt_bf16<<<1024, 256, 0, stream>>>(w1, w1bf, 262144);
    // conv1: out1r[b][256][4096] = w1bf @ xbfT   (xbfT dead after this)
    gemm_bf16<<<dim3(32, 2, 4), 256, 0, stream>>>(w1bf, xbfT, out1r, 256, 4096, 1024);
    gn_stats<<<128, 256, 0, stream>>>(out1r, st1, 256, 8);
    // GN1 apply -> bf16 bfA; shifted copy bfB
    gn1_apply_bf<<<4096, 256, 0, stream>>>(out1r, st1, g1s, g1b, bfA);
    mk_shift<<<16384, 256, 0, stream>>>(bfA, bfB);
    // offset conv (reads bfA)
    om_init<<<1728, 256, 0, stream>>>(om, bof);
    conv_off_k<<<dim3(16, 8, 4), 256, 0, stream>>>(bfA, wof, om);
    // weight conversions
    w2conv<<<2304, 256, 0, stream>>>(w2, w2bf);
    cvt_bf16<<<1024, 256, 0, stream>>>(w3, w3bf, 262144);
    // deformable einsum -> out2 (out1r region, now dead); 4 blocks/CU
    gemm2_mfma<<<dim3(256, 1, 4), 512, 0, stream>>>(bfA, bfB, w2bf, om, out2);
    // GN2 stats + fused apply/relu/transpose -> out2bT (bfA region, now dead)
    gn_stats<<<128, 256, 0, stream>>>(out2, st2, 256, 8);
    gn2t<<<dim3(64, 4, 4), 256, 0, stream>>>(out2, st2, g2s, g2b, out2bT);
    // conv3: out[b][1024][4096] = w3bf @ out2bT
    gemm_bf16<<<dim3(32, 8, 4), 256, 0, stream>>>(w3bf, out2bT, out, 1024, 4096, 256);
    gn_stats<<<128, 256, 0, stream>>>(out, st3, 1024, 32);
    final_k<<<16384, 256, 0, stream>>>(out, x, st3, g3s, g3b);
}

// Round 9
// 493.524 us; speedup vs baseline: 1.0907x; 1.0907x over previous
//
#include <hip/hip_runtime.h>
#include <math.h>

#define BATCH 4
#define CIN   1024
#define CB    256
#define HH    64
#define WW    64
#define PP    4096          // HH*WW
#define EPSV  1e-5f

using shortx8 = __attribute__((ext_vector_type(8))) short;
using floatx4 = __attribute__((ext_vector_type(4))) float;
using intx4   = __attribute__((ext_vector_type(4))) int;

static __device__ inline unsigned short f2bf(float f) {
    unsigned int u = __float_as_uint(f);
    u += 0x7fffu + ((u >> 16) & 1u);      // RNE
    return (unsigned short)(u >> 16);
}
static __device__ inline float bf2f(unsigned short s) {
    return __uint_as_float(((unsigned int)s) << 16);
}

// ---------------------------------------------------------------------------
// bf16 MFMA GEMM (conv1 / conv3). Unchanged from R4 (proven).
// ---------------------------------------------------------------------------
__global__ __launch_bounds__(256)
void gemm_bf16(const unsigned short* __restrict__ A,
               const unsigned short* __restrict__ BTg,
               float* __restrict__ Cg, int M, int N, int K) {
    const int b = blockIdx.z;
    const unsigned short* BT = BTg + (size_t)b * N * K;
    float* C = Cg + (size_t)b * M * N;
    const int m0 = blockIdx.y * 128;
    const int n0 = blockIdx.x * 128;
    const int tid = threadIdx.x;
    const int lane = tid & 63;
    const int wid = tid >> 6;
    const int l15 = lane & 15;
    const int quad = lane >> 4;

    __shared__ __align__(16) unsigned short As[128 * 40];
    __shared__ __align__(16) unsigned short Bs[128 * 40];

    floatx4 acc[2][8];
#pragma unroll
    for (int i = 0; i < 2; i++)
#pragma unroll
        for (int j = 0; j < 8; j++) acc[i][j] = (floatx4){0.f, 0.f, 0.f, 0.f};

    const int row = tid >> 1;
    const int half = tid & 1;

    for (int k0 = 0; k0 < K; k0 += 32) {
        const unsigned short* ga = A + (size_t)(m0 + row) * K + k0 + half * 16;
        const unsigned short* gb = BT + (size_t)(n0 + row) * K + k0 + half * 16;
        float4 a0 = *(const float4*)ga;
        float4 a1 = *(const float4*)(ga + 8);
        float4 b0 = *(const float4*)gb;
        float4 b1 = *(const float4*)(gb + 8);
        __syncthreads();
        *(float4*)((char*)As + row * 80 + half * 32) = a0;
        *(float4*)((char*)As + row * 80 + half * 32 + 16) = a1;
        *(float4*)((char*)Bs + row * 80 + half * 32) = b0;
        *(float4*)((char*)Bs + row * 80 + half * 32 + 16) = b1;
        __syncthreads();
        shortx8 af[2], bf[8];
#pragma unroll
        for (int i = 0; i < 2; i++)
            af[i] = *(const shortx8*)((const char*)As +
                    (wid * 32 + 16 * i + l15) * 80 + quad * 16);
#pragma unroll
        for (int j = 0; j < 8; j++)
            bf[j] = *(const shortx8*)((const char*)Bs +
                    (16 * j + l15) * 80 + quad * 16);
#pragma unroll
        for (int i = 0; i < 2; i++)
#pragma unroll
            for (int j = 0; j < 8; j++)
                acc[i][j] = __builtin_amdgcn_mfma_f32_16x16x32_bf16(
                    af[i], bf[j], acc[i][j], 0, 0, 0);
    }

#pragma unroll
    for (int i = 0; i < 2; i++) {
#pragma unroll
        for (int r = 0; r < 4; r++) {
            int m = m0 + wid * 32 + 16 * i + quad * 4 + r;
            float* dst = C + (size_t)m * N + n0 + l15;
#pragma unroll
            for (int j = 0; j < 8; j++)
                dst[16 * j] = acc[i][j][r];
        }
    }
}

// ---------------------------------------------------------------------------
// Tiled transpose + fp32->bf16: src [b][C][P] -> dst [b][P][C]
// ---------------------------------------------------------------------------
__global__ __launch_bounds__(256)
void transp_bf16(const float* __restrict__ src, unsigned short* __restrict__ dst,
                 int C, int P) {
    const int p0 = blockIdx.x * 64;
    const int c0 = blockIdx.y * 64;
    const int b = blockIdx.z;
    __shared__ unsigned short t[64][72];
    const float* s = src + ((size_t)b * C + c0) * P + p0;
    for (int e = threadIdx.x; e < 4096; e += 256) {
        int r = e >> 6, col = e & 63;
        t[r][col] = f2bf(s[(size_t)r * P + col]);
    }
    __syncthreads();
    unsigned short* d = dst + ((size_t)b * P + p0) * C + c0;
    for (int u = threadIdx.x; u < 512; u += 256) {
        int pr = u >> 3, c8 = (u & 7) * 8;
        ushort4 v0, v1;
        v0.x = t[c8 + 0][pr]; v0.y = t[c8 + 1][pr];
        v0.z = t[c8 + 2][pr]; v0.w = t[c8 + 3][pr];
        v1.x = t[c8 + 4][pr]; v1.y = t[c8 + 5][pr];
        v1.z = t[c8 + 6][pr]; v1.w = t[c8 + 7][pr];
        *(ushort4*)&d[(size_t)pr * C + c8] = v0;
        *(ushort4*)&d[(size_t)pr * C + c8 + 4] = v1;
    }
}

// ---------------------------------------------------------------------------
// GN2 apply + ReLU + transpose-convert: out2 fp32 [b][256][P] -> bf16 [b][P][256]
// ---------------------------------------------------------------------------
__global__ __launch_bounds__(256)
void gn2t(const float* __restrict__ src, const float2* __restrict__ st,
          const float* __restrict__ sc, const float* __restrict__ bi,
          unsigned short* __restrict__ dst) {
    const int p0 = blockIdx.x * 64;
    const int c0 = blockIdx.y * 64;
    const int b = blockIdx.z;
    __shared__ unsigned short t[64][72];
    const float* s = src + ((size_t)b * CB + c0) * PP + p0;
    for (int e = threadIdx.x; e < 4096; e += 256) {
        int r = e >> 6, col = e & 63;
        int c = c0 + r;
        float2 m = st[b * 32 + (c >> 3)];       // Cpg = 8
        float a = m.y * sc[c];
        float bb = bi[c] - m.x * a;
        t[r][col] = f2bf(fmaxf(s[(size_t)r * PP + col] * a + bb, 0.f));
    }
    __syncthreads();
    unsigned short* d = dst + ((size_t)b * PP + p0) * CB + c0;
    for (int u = threadIdx.x; u < 512; u += 256) {
        int pr = u >> 3, c8 = (u & 7) * 8;
        ushort4 v0, v1;
        v0.x = t[c8 + 0][pr]; v0.y = t[c8 + 1][pr];
        v0.z = t[c8 + 2][pr]; v0.w = t[c8 + 3][pr];
        v1.x = t[c8 + 4][pr]; v1.y = t[c8 + 5][pr];
        v1.z = t[c8 + 6][pr]; v1.w = t[c8 + 7][pr];
        *(ushort4*)&d[(size_t)pr * CB + c8] = v0;
        *(ushort4*)&d[(size_t)pr * CB + c8 + 4] = v1;
    }
}

// ---------------------------------------------------------------------------
__global__ __launch_bounds__(256)
void cvt_bf16(const float* __restrict__ s, unsigned short* __restrict__ d, int n) {
    int i = blockIdx.x * 256 + threadIdx.x;
    if (i < n) d[i] = f2bf(s[i]);
}

// ---------------------------------------------------------------------------
__global__ __launch_bounds__(256)
void gn_stats(const float* __restrict__ src, float2* __restrict__ stats,
              int C, int Cpg) {
    int bg = blockIdx.x;
    int b = bg >> 5, g = bg & 31;
    const float* base = src + ((size_t)b * C + (size_t)g * Cpg) * PP;
    int cnt = Cpg * PP;
    float s = 0.f, ss = 0.f;
    const float4* p4 = (const float4*)base;
    int n4 = cnt >> 2;
    for (int i = threadIdx.x; i < n4; i += 256) {
        float4 v = p4[i];
        s += v.x + v.y + v.z + v.w;
        ss += v.x * v.x + v.y * v.y + v.z * v.z + v.w * v.w;
    }
    for (int off = 32; off > 0; off >>= 1) {
        s += __shfl_down(s, off, 64);
        ss += __shfl_down(ss, off, 64);
    }
    __shared__ float rs[4], rss[4];
    int lane = threadIdx.x & 63, wid = threadIdx.x >> 6;
    if (lane == 0) { rs[wid] = s; rss[wid] = ss; }
    __syncthreads();
    if (threadIdx.x == 0) {
        float S = rs[0] + rs[1] + rs[2] + rs[3];
        float SS = rss[0] + rss[1] + rss[2] + rss[3];
        float mean = S / (float)cnt;
        float var = SS / (float)cnt - mean * mean;
        stats[bg] = make_float2(mean, rsqrtf(var + EPSV));
    }
}

// ---------------------------------------------------------------------------
// GN1 apply + ReLU, fp32 in -> bf16 out (bfA). C=256, Cpg=8 hardcoded.
// ---------------------------------------------------------------------------
__global__ __launch_bounds__(256)
void gn1_apply_bf(const float* __restrict__ src, const float2* __restrict__ stats,
                  const float* __restrict__ sc, const float* __restrict__ bi,
                  unsigned short* __restrict__ dst) {
    long i = (long)blockIdx.x * 256 + threadIdx.x;
    long total4 = ((long)BATCH * CB * PP) >> 2;
    if (i >= total4) return;
    long e = i << 2;
    int c = (int)((e >> 12) & 255);
    int b = (int)(e >> 20);
    float2 st = stats[b * 32 + (c >> 3)];
    float a = st.y * sc[c];
    float bb = bi[c] - st.x * a;
    float4 v = ((const float4*)src)[i];
    ushort4 o;
    o.x = f2bf(fmaxf(v.x * a + bb, 0.f));
    o.y = f2bf(fmaxf(v.y * a + bb, 0.f));
    o.z = f2bf(fmaxf(v.z * a + bb, 0.f));
    o.w = f2bf(fmaxf(v.w * a + bb, 0.f));
    ((ushort4*)dst)[i] = o;
}

// ---------------------------------------------------------------------------
// bfB[m] = bfA[m+1] (flat shift; boundary dwords never used by gathers).
// ---------------------------------------------------------------------------
__global__ __launch_bounds__(256)
void mk_shift(const unsigned short* __restrict__ a, unsigned short* __restrict__ bsh) {
    int t = blockIdx.x * 256 + threadIdx.x;
    uint2 d01 = ((const uint2*)a)[t];
    unsigned int d2 = ((const unsigned int*)a)[2 * t + 2];
    unsigned int w0 = (d01.x >> 16) | (d01.y << 16);
    unsigned int w1 = (d01.y >> 16) | (d2 << 16);
    ((uint2*)bsh)[t] = make_uint2(w0, w1);
}

// ---------------------------------------------------------------------------
__global__ __launch_bounds__(256)
void om_init(float* __restrict__ om, const float* __restrict__ boff) {
    int t = blockIdx.x * 256 + threadIdx.x;
    if (t < BATCH * 27 * PP) {
        int r = (t >> 12) % 27;
        om[t] = boff[r];
    }
}

// ---------------------------------------------------------------------------
// 3x3 offset conv (R8 version: 8-channel strip staging, 8 barriers total).
// ---------------------------------------------------------------------------
__global__ __launch_bounds__(256)
void conv_off_k(const unsigned short* __restrict__ o1bf, const float* __restrict__ w_off,
                float* __restrict__ om) {
    const int y0 = blockIdx.x * 4;
    const int c0 = blockIdx.y * 32;
    const int b = blockIdx.z;
    const int tid = threadIdx.x;
    const int tx = tid & 63, ty = tid >> 6;

    __shared__ __align__(16) float Aall[32 * 384];   // 48 KB
    __shared__ float strip[8 * 384];                 // 12 KB

    for (int e = tid; e < 32 * 384; e += 256) {
        int c = e / 384;
        int rk = e % 384;
        int r = rk / 12, k = rk % 12;
        float v = 0.f;
        if (r < 27 && k < 9) v = w_off[((size_t)r * CB + (c0 + c)) * 9 + k];
        Aall[e] = v;
    }

    float acc[8][4];
#pragma unroll
    for (int i = 0; i < 8; i++)
#pragma unroll
        for (int j = 0; j < 4; j++) acc[i][j] = 0.f;

    for (int cg = 0; cg < 4; cg++) {
        __syncthreads();
        for (int e = tid; e < 8 * 384; e += 256) {
            int c = e / 384, rk = e % 384;
            int r = rk >> 6, col = rk & 63;
            int gy = y0 + r - 1;
            strip[e] = (gy >= 0 && gy < 64)
                ? bf2f(o1bf[(((size_t)b * CB + c0 + cg * 8 + c) << 12) + (gy << 6) + col])
                : 0.f;
        }
        __syncthreads();
        for (int c = 0; c < 8; c++) {
            float v[6][3];
#pragma unroll
            for (int r = 0; r < 6; r++)
#pragma unroll
                for (int d = 0; d < 3; d++) {
                    int col = tx + d - 1;
                    v[r][d] = (col >= 0 && col < 64) ? strip[c * 384 + r * 64 + col] : 0.f;
                }
            const float* Ac = &Aall[(cg * 8 + c) * 384];
#pragma unroll
            for (int i = 0; i < 8; i++) {
                int m = ty + 4 * i;
                float4 w0 = *(const float4*)(Ac + m * 12);
                float4 w1v = *(const float4*)(Ac + m * 12 + 4);
                float w8 = Ac[m * 12 + 8];
                float wk[9] = {w0.x, w0.y, w0.z, w0.w, w1v.x, w1v.y, w1v.z, w1v.w, w8};
#pragma unroll
                for (int kk = 0; kk < 9; kk++) {
                    int dy = kk / 3, dx = kk % 3;
#pragma unroll
                    for (int j = 0; j < 4; j++)
                        acc[i][j] += wk[kk] * v[j + dy][dx];
                }
            }
        }
    }
#pragma unroll
    for (int i = 0; i < 8; i++) {
        int m = ty + 4 * i;
        if (m < 27) {
#pragma unroll
            for (int j = 0; j < 4; j++) {
                int p = ((y0 + j) << 6) + tx;
                atomicAdd(&om[((size_t)b * 27 + m) * PP + p], acc[i][j]);
            }
        }
    }
}

// ---------------------------------------------------------------------------
// w2 fp32 [o][c][tap] -> bf16, K reordered: w2bf[o][tap*256 + c]
// ---------------------------------------------------------------------------
__global__ __launch_bounds__(256)
void w2conv(const float* __restrict__ w2, unsigned short* __restrict__ w2bf) {
    int t = blockIdx.x * 256 + threadIdx.x;
    if (t >= 256 * 2304) return;
    int o = t / 2304;
    int r = t - o * 2304;
    int tap = r >> 8, c = r & 255;
    w2bf[t] = f2bf(w2[((size_t)o * 256 + c) * 9 + tap]);
}

// ---------------------------------------------------------------------------
// Deformable einsum, bf16 MFMA. R9: BN=32 / grid 512 (R7-proven config) with
// (1) BK=64 -> 36 barrier iterations instead of 72, 8-gather batches;
// (2) A-fragments loaded DIRECTLY from global w2bf (L2-resident, 16B/lane),
//     no A LDS staging -> barrier protects only the 4.6KB Bs tile.
// Straight-line skeleton, no register rotation across barriers (R5 lesson).
// ---------------------------------------------------------------------------
__global__ __launch_bounds__(512)
void gemm2_mfma(const unsigned short* __restrict__ bfA,
                const unsigned short* __restrict__ bfB,
                const unsigned short* __restrict__ w2bf,
                const float* __restrict__ om, float* __restrict__ out2) {
    const int p0 = blockIdx.x * 32;
    const int b = blockIdx.z;
    const int tid = threadIdx.x;
    const int lane = tid & 63;
    const int wid = tid >> 6;          // 0..7
    const int l15 = lane & 15;
    const int quad = lane >> 4;        // 0..3

    __shared__ __align__(16) unsigned short Bs[32 * 72];   // [pixel][64ch+8 pad] 4.5 KB
    __shared__ __align__(16) float swL[9 * 32 * 4];        // 4.5 KB
    __shared__ __align__(16) int   siL[9 * 32 * 2];        // 2.25 KB

    // inline samp_prep with pair-swizzled weights (32 pixels x 9 taps)
    const float* ob = om + (size_t)b * 27 * PP;
    for (int e = tid; e < 288; e += 512) {
        int k = e >> 5, p = e & 31;
        int pg = p0 + p;
        float offx = ob[(size_t)k * PP + pg];
        float offy = ob[(size_t)(9 + k) * PP + pg];
        float ms = 1.f / (1.f + expf(-ob[(size_t)(18 + k) * PP + pg]));
        int y = pg >> 6, x = pg & 63;
        float py = (float)(y + k / 3 - 1) + offy;
        float px = (float)(x + (k % 3) - 1) + offx;
        float y0f = floorf(py), x0f = floorf(px);
        float wy1 = py - y0f, wx1 = px - x0f;
        int iy0 = (int)y0f, ix0 = (int)x0f;
        int iy1 = iy0 + 1;
        float wy0v = (iy0 >= 0 && iy0 < 64) ? (1.f - wy1) * ms : 0.f;
        float wy1v = (iy1 >= 0 && iy1 < 64) ? wy1 * ms : 0.f;
        int cy0 = min(max(iy0, 0), 63), cy1 = min(max(iy1, 0), 63);
        float xa, xb; int q;
        if (ix0 >= 0 && ix0 <= 62)      { q = ix0; xa = 1.f - wx1; xb = wx1;       }
        else if (ix0 == -1)             { q = 0;   xa = wx1;       xb = 0.f;       }
        else if (ix0 == 63)             { q = 62;  xa = 0.f;       xb = 1.f - wx1; }
        else                            { q = 0;   xa = 0.f;       xb = 0.f;       }
        swL[e * 4 + 0] = wy0v * xa;
        swL[e * 4 + 1] = wy0v * xb;
        swL[e * 4 + 2] = wy1v * xa;
        swL[e * 4 + 3] = wy1v * xb;
        siL[e * 2 + 0] = (cy0 << 6) + q;
        siL[e * 2 + 1] = (cy1 << 6) + q;
    }

    floatx4 acc[2][2];
#pragma unroll
    for (int i = 0; i < 2; i++)
#pragma unroll
        for (int j = 0; j < 2; j++) acc[i][j] = (floatx4){0.f, 0.f, 0.f, 0.f};

    const int bp = tid & 31;           // pixel within tile
    const int cq = tid >> 5;           // 0..15, 4 channels each (of 64)
    const size_t chbase = ((size_t)b * CB) << 12;
    const int mbase = wid * 32;

    __syncthreads();   // tables ready

    for (int cc = 0; cc < 4; cc++) {
        const int c0 = cc * 64;
        for (int tap = 0; tap < 9; tap++) {
            // ---- B build: 4 channels for pixel bp (8 gather dwords, batched)
            floatx4 wv = *(const floatx4*)&swL[(tap * 32 + bp) * 4];
            int i0 = siL[(tap * 32 + bp) * 2 + 0];
            int i1 = siL[(tap * 32 + bp) * 2 + 1];
            const unsigned short* bs0 = (i0 & 1) ? bfB : bfA;
            unsigned short bvv[4];
#pragma unroll
            for (int s = 0; s < 4; s++) {
                size_t co = chbase + ((size_t)(c0 + cq * 4 + s) << 12);
                unsigned int d0 = *(const unsigned int*)(bs0 + co + (i0 & ~1));
                unsigned int d1 = *(const unsigned int*)(bs0 + co + (i1 & ~1));
                float acv = wv[0] * __uint_as_float(d0 << 16)
                          + wv[1] * __uint_as_float(d0 & 0xffff0000u)
                          + wv[2] * __uint_as_float(d1 << 16)
                          + wv[3] * __uint_as_float(d1 & 0xffff0000u);
                bvv[s] = f2bf(acv);
            }
            *(ushort4*)((char*)Bs + bp * 144 + cq * 8) =
                make_ushort4(bvv[0], bvv[1], bvv[2], bvv[3]);
            __syncthreads();   // Bs ready
            // ---- MFMA phase: A direct from global (L2), B from LDS
            const int kb = tap * 256 + c0;
#pragma unroll
            for (int h = 0; h < 2; h++) {
                shortx8 af[2], bfr[2];
#pragma unroll
                for (int i = 0; i < 2; i++)
                    af[i] = *(const shortx8*)(w2bf +
                            (size_t)(mbase + 16 * i + l15) * 2304 +
                            kb + h * 32 + quad * 8);
#pragma unroll
                for (int j = 0; j < 2; j++)
                    bfr[j] = *(const shortx8*)((const char*)Bs +
                            (16 * j + l15) * 144 + h * 64 + quad * 16);
#pragma unroll
                for (int i = 0; i < 2; i++)
#pragma unroll
                    for (int j = 0; j < 2; j++)
                        acc[i][j] = __builtin_amdgcn_mfma_f32_16x16x32_bf16(
                            af[i], bfr[j], acc[i][j], 0, 0, 0);
            }
            __syncthreads();   // Bs consumed
        }
    }

    // epilogue: D col = lane&15, row = quad*4+reg
#pragma unroll
    for (int i = 0; i < 2; i++) {
#pragma unroll
        for (int r = 0; r < 4; r++) {
            int row = mbase + 16 * i + quad * 4 + r;
            float* dst = out2 + chbase + ((size_t)row << 12) + p0 + l15;
#pragma unroll
            for (int j = 0; j < 2; j++)
                dst[16 * j] = acc[i][j][r];
        }
    }
}

// ---------------------------------------------------------------------------
// Final: relu(gn3(d_out)*sc+bi + x) in place.
// ---------------------------------------------------------------------------
__global__ __launch_bounds__(256)
void final_k(float* __restrict__ dout, const float* __restrict__ x,
             const float2* __restrict__ stats, const float* __restrict__ sc,
             const float* __restrict__ bi) {
    long i = (long)blockIdx.x * 256 + threadIdx.x;
    long total4 = ((long)BATCH * CIN * PP) >> 2;
    if (i >= total4) return;
    long e = i << 2;
    int c = (int)((e >> 12) & 1023);
    int b = (int)(e >> 22);
    float2 st = stats[b * 32 + (c >> 5)];
    float a = st.y * sc[c];
    float bb = bi[c] - st.x * a;
    float4 v = ((float4*)dout)[i];
    float4 xv = ((const float4*)x)[i];
    v.x = fmaxf(v.x * a + bb + xv.x, 0.f);
    v.y = fmaxf(v.y * a + bb + xv.y, 0.f);
    v.z = fmaxf(v.z * a + bb + xv.z, 0.f);
    v.w = fmaxf(v.w * a + bb + xv.w, 0.f);
    ((float4*)dout)[i] = v;
}

// ---------------------------------------------------------------------------
// Workspace layout identical to R7/R8 (50.9 MB, verified).
// ---------------------------------------------------------------------------
extern "C" void kernel_launch(void* const* d_in, const int* in_sizes, int n_in,
                              void* d_out, int out_size, void* d_ws, size_t ws_size,
                              hipStream_t stream) {
    const float* x   = (const float*)d_in[0];
    const float* w1  = (const float*)d_in[1];
    const float* g1s = (const float*)d_in[2];
    const float* g1b = (const float*)d_in[3];
    const float* wof = (const float*)d_in[4];
    const float* bof = (const float*)d_in[5];
    const float* w2  = (const float*)d_in[6];
    const float* g2s = (const float*)d_in[7];
    const float* g2b = (const float*)d_in[8];
    const float* w3  = (const float*)d_in[9];
    const float* g3s = (const float*)d_in[10];
    const float* g3b = (const float*)d_in[11];
    float* out = (float*)d_out;

    float* ws = (float*)d_ws;
    unsigned short* w1bf   = (unsigned short*)(ws + 0);
    float*          out1r  = ws + 131072;               // conv1 raw out
    float*          out2   = ws + 131072;               // aliases out1r (dead)
    unsigned short* xbfT   = (unsigned short*)(ws + 4325376);
    unsigned short* bfA    = (unsigned short*)(ws + 4325376);
    unsigned short* bfB    = (unsigned short*)(ws + 6422528);
    float*          om     = ws + 8519680;
    unsigned short* w2bf   = (unsigned short*)(ws + 8962048);
    unsigned short* out2bT = (unsigned short*)(ws + 4325376); // aliases bfA (dead)
    unsigned short* w3bf   = (unsigned short*)(ws + 11354112);
    float2* st1 = (float2*)(ws + 11485184);
    float2* st2 = st1 + 128;
    float2* st3 = st2 + 128;

    // x [b][1024][4096] -> xbfT [b][4096][1024] bf16
    transp_bf16<<<dim3(64, 16, 4), 256, 0, stream>>>(x, xbfT, 1024, 4096);
    cvt_bf16<<<1024, 256, 0, stream>>>(w1, w1bf, 262144);
    // conv1: out1r[b][256][4096] = w1bf @ xbfT   (xbfT dead after this)
    gemm_bf16<<<dim3(32, 2, 4), 256, 0, stream>>>(w1bf, xbfT, out1r, 256, 4096, 1024);
    gn_stats<<<128, 256, 0, stream>>>(out1r, st1, 256, 8);
    // GN1 apply -> bf16 bfA; shifted copy bfB
    gn1_apply_bf<<<4096, 256, 0, stream>>>(out1r, st1, g1s, g1b, bfA);
    mk_shift<<<16384, 256, 0, stream>>>(bfA, bfB);
    // offset conv (reads bfA)
    om_init<<<1728, 256, 0, stream>>>(om, bof);
    conv_off_k<<<dim3(16, 8, 4), 256, 0, stream>>>(bfA, wof, om);
    // weight conversions
    w2conv<<<2304, 256, 0, stream>>>(w2, w2bf);
    cvt_bf16<<<1024, 256, 0, stream>>>(w3, w3bf, 262144);
    // deformable einsum -> out2 (out1r region, now dead); BN=32, 2 blocks/CU
    gemm2_mfma<<<dim3(128, 1, 4), 512, 0, stream>>>(bfA, bfB, w2bf, om, out2);
    // GN2 stats + fused apply/relu/transpose -> out2bT (bfA region, now dead)
    gn_stats<<<128, 256, 0, stream>>>(out2, st2, 256, 8);
    gn2t<<<dim3(64, 4, 4), 256, 0, stream>>>(out2, st2, g2s, g2b, out2bT);
    // conv3: out[b][1024][4096] = w3bf @ out2bT
    gemm_bf16<<<dim3(32, 8, 4), 256, 0, stream>>>(w3bf, out2bT, out, 1024, 4096, 256);
    gn_stats<<<128, 256, 0, stream>>>(out, st3, 1024, 32);
    final_k<<<16384, 256, 0, stream>>>(out, x, st3, g3s, g3b);
}

// Round 10
// 478.683 us; speedup vs baseline: 1.1245x; 1.0310x over previous
//
#include <hip/hip_runtime.h>
#include <math.h>

#define BATCH 4
#define CIN   1024
#define CB    256
#define HH    64
#define WW    64
#define PP    4096          // HH*WW
#define EPSV  1e-5f

using shortx8 = __attribute__((ext_vector_type(8))) short;
using floatx4 = __attribute__((ext_vector_type(4))) float;
using intx4   = __attribute__((ext_vector_type(4))) int;

static __device__ inline unsigned short f2bf(float f) {
    unsigned int u = __float_as_uint(f);
    u += 0x7fffu + ((u >> 16) & 1u);      // RNE
    return (unsigned short)(u >> 16);
}
static __device__ inline float bf2f(unsigned short s) {
    return __uint_as_float(((unsigned int)s) << 16);
}

// ---------------------------------------------------------------------------
// bf16 MFMA GEMM (conv1 / conv3). Unchanged from R4 (proven).
// ---------------------------------------------------------------------------
__global__ __launch_bounds__(256)
void gemm_bf16(const unsigned short* __restrict__ A,
               const unsigned short* __restrict__ BTg,
               float* __restrict__ Cg, int M, int N, int K) {
    const int b = blockIdx.z;
    const unsigned short* BT = BTg + (size_t)b * N * K;
    float* C = Cg + (size_t)b * M * N;
    const int m0 = blockIdx.y * 128;
    const int n0 = blockIdx.x * 128;
    const int tid = threadIdx.x;
    const int lane = tid & 63;
    const int wid = tid >> 6;
    const int l15 = lane & 15;
    const int quad = lane >> 4;

    __shared__ __align__(16) unsigned short As[128 * 40];
    __shared__ __align__(16) unsigned short Bs[128 * 40];

    floatx4 acc[2][8];
#pragma unroll
    for (int i = 0; i < 2; i++)
#pragma unroll
        for (int j = 0; j < 8; j++) acc[i][j] = (floatx4){0.f, 0.f, 0.f, 0.f};

    const int row = tid >> 1;
    const int half = tid & 1;

    for (int k0 = 0; k0 < K; k0 += 32) {
        const unsigned short* ga = A + (size_t)(m0 + row) * K + k0 + half * 16;
        const unsigned short* gb = BT + (size_t)(n0 + row) * K + k0 + half * 16;
        float4 a0 = *(const float4*)ga;
        float4 a1 = *(const float4*)(ga + 8);
        float4 b0 = *(const float4*)gb;
        float4 b1 = *(const float4*)(gb + 8);
        __syncthreads();
        *(float4*)((char*)As + row * 80 + half * 32) = a0;
        *(float4*)((char*)As + row * 80 + half * 32 + 16) = a1;
        *(float4*)((char*)Bs + row * 80 + half * 32) = b0;
        *(float4*)((char*)Bs + row * 80 + half * 32 + 16) = b1;
        __syncthreads();
        shortx8 af[2], bf[8];
#pragma unroll
        for (int i = 0; i < 2; i++)
            af[i] = *(const shortx8*)((const char*)As +
                    (wid * 32 + 16 * i + l15) * 80 + quad * 16);
#pragma unroll
        for (int j = 0; j < 8; j++)
            bf[j] = *(const shortx8*)((const char*)Bs +
                    (16 * j + l15) * 80 + quad * 16);
#pragma unroll
        for (int i = 0; i < 2; i++)
#pragma unroll
            for (int j = 0; j < 8; j++)
                acc[i][j] = __builtin_amdgcn_mfma_f32_16x16x32_bf16(
                    af[i], bf[j], acc[i][j], 0, 0, 0);
    }

#pragma unroll
    for (int i = 0; i < 2; i++) {
#pragma unroll
        for (int r = 0; r < 4; r++) {
            int m = m0 + wid * 32 + 16 * i + quad * 4 + r;
            float* dst = C + (size_t)m * N + n0 + l15;
#pragma unroll
            for (int j = 0; j < 8; j++)
                dst[16 * j] = acc[i][j][r];
        }
    }
}

// ---------------------------------------------------------------------------
// Tiled transpose + fp32->bf16: src [b][C][P] -> dst [b][P][C]
// ---------------------------------------------------------------------------
__global__ __launch_bounds__(256)
void transp_bf16(const float* __restrict__ src, unsigned short* __restrict__ dst,
                 int C, int P) {
    const int p0 = blockIdx.x * 64;
    const int c0 = blockIdx.y * 64;
    const int b = blockIdx.z;
    __shared__ unsigned short t[64][72];
    const float* s = src + ((size_t)b * C + c0) * P + p0;
    for (int e = threadIdx.x; e < 4096; e += 256) {
        int r = e >> 6, col = e & 63;
        t[r][col] = f2bf(s[(size_t)r * P + col]);
    }
    __syncthreads();
    unsigned short* d = dst + ((size_t)b * P + p0) * C + c0;
    for (int u = threadIdx.x; u < 512; u += 256) {
        int pr = u >> 3, c8 = (u & 7) * 8;
        ushort4 v0, v1;
        v0.x = t[c8 + 0][pr]; v0.y = t[c8 + 1][pr];
        v0.z = t[c8 + 2][pr]; v0.w = t[c8 + 3][pr];
        v1.x = t[c8 + 4][pr]; v1.y = t[c8 + 5][pr];
        v1.z = t[c8 + 6][pr]; v1.w = t[c8 + 7][pr];
        *(ushort4*)&d[(size_t)pr * C + c8] = v0;
        *(ushort4*)&d[(size_t)pr * C + c8 + 4] = v1;
    }
}

// ---------------------------------------------------------------------------
// GN2 apply + ReLU + transpose-convert: out2 fp32 [b][256][P] -> bf16 [b][P][256]
// ---------------------------------------------------------------------------
__global__ __launch_bounds__(256)
void gn2t(const float* __restrict__ src, const float2* __restrict__ st,
          const float* __restrict__ sc, const float* __restrict__ bi,
          unsigned short* __restrict__ dst) {
    const int p0 = blockIdx.x * 64;
    const int c0 = blockIdx.y * 64;
    const int b = blockIdx.z;
    __shared__ unsigned short t[64][72];
    const float* s = src + ((size_t)b * CB + c0) * PP + p0;
    for (int e = threadIdx.x; e < 4096; e += 256) {
        int r = e >> 6, col = e & 63;
        int c = c0 + r;
        float2 m = st[b * 32 + (c >> 3)];       // Cpg = 8
        float a = m.y * sc[c];
        float bb = bi[c] - m.x * a;
        t[r][col] = f2bf(fmaxf(s[(size_t)r * PP + col] * a + bb, 0.f));
    }
    __syncthreads();
    unsigned short* d = dst + ((size_t)b * PP + p0) * CB + c0;
    for (int u = threadIdx.x; u < 512; u += 256) {
        int pr = u >> 3, c8 = (u & 7) * 8;
        ushort4 v0, v1;
        v0.x = t[c8 + 0][pr]; v0.y = t[c8 + 1][pr];
        v0.z = t[c8 + 2][pr]; v0.w = t[c8 + 3][pr];
        v1.x = t[c8 + 4][pr]; v1.y = t[c8 + 5][pr];
        v1.z = t[c8 + 6][pr]; v1.w = t[c8 + 7][pr];
        *(ushort4*)&d[(size_t)pr * CB + c8] = v0;
        *(ushort4*)&d[(size_t)pr * CB + c8 + 4] = v1;
    }
}

// ---------------------------------------------------------------------------
__global__ __launch_bounds__(256)
void cvt_bf16(const float* __restrict__ s, unsigned short* __restrict__ d, int n) {
    int i = blockIdx.x * 256 + threadIdx.x;
    if (i < n) d[i] = f2bf(s[i]);
}

// ---------------------------------------------------------------------------
__global__ __launch_bounds__(256)
void gn_stats(const float* __restrict__ src, float2* __restrict__ stats,
              int C, int Cpg) {
    int bg = blockIdx.x;
    int b = bg >> 5, g = bg & 31;
    const float* base = src + ((size_t)b * C + (size_t)g * Cpg) * PP;
    int cnt = Cpg * PP;
    float s = 0.f, ss = 0.f;
    const float4* p4 = (const float4*)base;
    int n4 = cnt >> 2;
    for (int i = threadIdx.x; i < n4; i += 256) {
        float4 v = p4[i];
        s += v.x + v.y + v.z + v.w;
        ss += v.x * v.x + v.y * v.y + v.z * v.z + v.w * v.w;
    }
    for (int off = 32; off > 0; off >>= 1) {
        s += __shfl_down(s, off, 64);
        ss += __shfl_down(ss, off, 64);
    }
    __shared__ float rs[4], rss[4];
    int lane = threadIdx.x & 63, wid = threadIdx.x >> 6;
    if (lane == 0) { rs[wid] = s; rss[wid] = ss; }
    __syncthreads();
    if (threadIdx.x == 0) {
        float S = rs[0] + rs[1] + rs[2] + rs[3];
        float SS = rss[0] + rss[1] + rss[2] + rss[3];
        float mean = S / (float)cnt;
        float var = SS / (float)cnt - mean * mean;
        stats[bg] = make_float2(mean, rsqrtf(var + EPSV));
    }
}

// ---------------------------------------------------------------------------
// GN1 apply + ReLU, fp32 in -> bf16 out (bfA). C=256, Cpg=8 hardcoded.
// ---------------------------------------------------------------------------
__global__ __launch_bounds__(256)
void gn1_apply_bf(const float* __restrict__ src, const float2* __restrict__ stats,
                  const float* __restrict__ sc, const float* __restrict__ bi,
                  unsigned short* __restrict__ dst) {
    long i = (long)blockIdx.x * 256 + threadIdx.x;
    long total4 = ((long)BATCH * CB * PP) >> 2;
    if (i >= total4) return;
    long e = i << 2;
    int c = (int)((e >> 12) & 255);
    int b = (int)(e >> 20);
    float2 st = stats[b * 32 + (c >> 3)];
    float a = st.y * sc[c];
    float bb = bi[c] - st.x * a;
    float4 v = ((const float4*)src)[i];
    ushort4 o;
    o.x = f2bf(fmaxf(v.x * a + bb, 0.f));
    o.y = f2bf(fmaxf(v.y * a + bb, 0.f));
    o.z = f2bf(fmaxf(v.z * a + bb, 0.f));
    o.w = f2bf(fmaxf(v.w * a + bb, 0.f));
    ((ushort4*)dst)[i] = o;
}

// ---------------------------------------------------------------------------
// bfB[m] = bfA[m+1] (flat shift; boundary dwords never used by gathers).
// ---------------------------------------------------------------------------
__global__ __launch_bounds__(256)
void mk_shift(const unsigned short* __restrict__ a, unsigned short* __restrict__ bsh) {
    int t = blockIdx.x * 256 + threadIdx.x;
    uint2 d01 = ((const uint2*)a)[t];
    unsigned int d2 = ((const unsigned int*)a)[2 * t + 2];
    unsigned int w0 = (d01.x >> 16) | (d01.y << 16);
    unsigned int w1 = (d01.y >> 16) | (d2 << 16);
    ((uint2*)bsh)[t] = make_uint2(w0, w1);
}

// ---------------------------------------------------------------------------
__global__ __launch_bounds__(256)
void om_init(float* __restrict__ om, const float* __restrict__ boff) {
    int t = blockIdx.x * 256 + threadIdx.x;
    if (t < BATCH * 27 * PP) {
        int r = (t >> 12) % 27;
        om[t] = boff[r];
    }
}

// ---------------------------------------------------------------------------
// 3x3 offset conv (R8 version: 8-channel strip staging, 8 barriers total).
// ---------------------------------------------------------------------------
__global__ __launch_bounds__(256)
void conv_off_k(const unsigned short* __restrict__ o1bf, const float* __restrict__ w_off,
                float* __restrict__ om) {
    const int y0 = blockIdx.x * 4;
    const int c0 = blockIdx.y * 32;
    const int b = blockIdx.z;
    const int tid = threadIdx.x;
    const int tx = tid & 63, ty = tid >> 6;

    __shared__ __align__(16) float Aall[32 * 384];   // 48 KB
    __shared__ float strip[8 * 384];                 // 12 KB

    for (int e = tid; e < 32 * 384; e += 256) {
        int c = e / 384;
        int rk = e % 384;
        int r = rk / 12, k = rk % 12;
        float v = 0.f;
        if (r < 27 && k < 9) v = w_off[((size_t)r * CB + (c0 + c)) * 9 + k];
        Aall[e] = v;
    }

    float acc[8][4];
#pragma unroll
    for (int i = 0; i < 8; i++)
#pragma unroll
        for (int j = 0; j < 4; j++) acc[i][j] = 0.f;

    for (int cg = 0; cg < 4; cg++) {
        __syncthreads();
        for (int e = tid; e < 8 * 384; e += 256) {
            int c = e / 384, rk = e % 384;
            int r = rk >> 6, col = rk & 63;
            int gy = y0 + r - 1;
            strip[e] = (gy >= 0 && gy < 64)
                ? bf2f(o1bf[(((size_t)b * CB + c0 + cg * 8 + c) << 12) + (gy << 6) + col])
                : 0.f;
        }
        __syncthreads();
        for (int c = 0; c < 8; c++) {
            float v[6][3];
#pragma unroll
            for (int r = 0; r < 6; r++)
#pragma unroll
                for (int d = 0; d < 3; d++) {
                    int col = tx + d - 1;
                    v[r][d] = (col >= 0 && col < 64) ? strip[c * 384 + r * 64 + col] : 0.f;
                }
            const float* Ac = &Aall[(cg * 8 + c) * 384];
#pragma unroll
            for (int i = 0; i < 8; i++) {
                int m = ty + 4 * i;
                float4 w0 = *(const float4*)(Ac + m * 12);
                float4 w1v = *(const float4*)(Ac + m * 12 + 4);
                float w8 = Ac[m * 12 + 8];
                float wk[9] = {w0.x, w0.y, w0.z, w0.w, w1v.x, w1v.y, w1v.z, w1v.w, w8};
#pragma unroll
                for (int kk = 0; kk < 9; kk++) {
                    int dy = kk / 3, dx = kk % 3;
#pragma unroll
                    for (int j = 0; j < 4; j++)
                        acc[i][j] += wk[kk] * v[j + dy][dx];
                }
            }
        }
    }
#pragma unroll
    for (int i = 0; i < 8; i++) {
        int m = ty + 4 * i;
        if (m < 27) {
#pragma unroll
            for (int j = 0; j < 4; j++) {
                int p = ((y0 + j) << 6) + tx;
                atomicAdd(&om[((size_t)b * 27 + m) * PP + p], acc[i][j]);
            }
        }
    }
}

// ---------------------------------------------------------------------------
// w2 fp32 [o][c][tap] -> bf16, K reordered: w2bf[o][tap*256 + c]
// ---------------------------------------------------------------------------
__global__ __launch_bounds__(256)
void w2conv(const float* __restrict__ w2, unsigned short* __restrict__ w2bf) {
    int t = blockIdx.x * 256 + threadIdx.x;
    if (t >= 256 * 2304) return;
    int o = t / 2304;
    int r = t - o * 2304;
    int tap = r >> 8, c = r & 255;
    w2bf[t] = f2bf(w2[((size_t)o * 256 + c) * 9 + tap]);
}

// ---------------------------------------------------------------------------
// Deformable einsum, bf16 MFMA. R10: body = R7's best-measured version
// (BN=32, BK=32, A via LDS, dual-aligned bf16 gathers, cc-outer/tap-inner).
// ONE change: XCD<->batch affinity swizzle. Grid = 512 linear blocks;
// assuming gfx950's round-robin dispatch (xcd ~ blk%8), XCD pair {2b,2b+1}
// serves only batch b -> per-XCD gather working set 4.2 MB ~= L2-resident
// instead of 16.8 MB (all 4 batches) thrashing every XCD L2.
// ---------------------------------------------------------------------------
__global__ __launch_bounds__(512)
void gemm2_mfma(const unsigned short* __restrict__ bfA,
                const unsigned short* __restrict__ bfB,
                const unsigned short* __restrict__ w2bf,
                const float* __restrict__ om, float* __restrict__ out2) {
    const int blk = blockIdx.x;
    const int xcd = blk & 7;
    const int b = xcd >> 1;                          // batch per XCD-pair
    const int p0 = (((blk >> 3) << 1) | (xcd & 1)) * 32;
    const int tid = threadIdx.x;
    const int lane = tid & 63;
    const int wid = tid >> 6;          // 0..7
    const int l15 = lane & 15;
    const int quad = lane >> 4;        // 0..3

    __shared__ __align__(16) unsigned short As[256 * 40];  // 20.0 KB
    __shared__ __align__(16) unsigned short Bs[32 * 40];   //  2.5 KB
    __shared__ __align__(16) float swL[9 * 32 * 4];        //  4.5 KB
    __shared__ __align__(16) int   siL[9 * 32 * 2];        //  2.25 KB

    // inline samp_prep with pair-swizzled weights
    const float* ob = om + (size_t)b * 27 * PP;
    for (int e = tid; e < 288; e += 512) {
        int k = e >> 5, p = e & 31;
        int pg = p0 + p;
        float offx = ob[(size_t)k * PP + pg];
        float offy = ob[(size_t)(9 + k) * PP + pg];
        float ms = 1.f / (1.f + expf(-ob[(size_t)(18 + k) * PP + pg]));
        int y = pg >> 6, x = pg & 63;
        float py = (float)(y + k / 3 - 1) + offy;
        float px = (float)(x + (k % 3) - 1) + offx;
        float y0f = floorf(py), x0f = floorf(px);
        float wy1 = py - y0f, wx1 = px - x0f;
        int iy0 = (int)y0f, ix0 = (int)x0f;
        int iy1 = iy0 + 1;
        float wy0v = (iy0 >= 0 && iy0 < 64) ? (1.f - wy1) * ms : 0.f;
        float wy1v = (iy1 >= 0 && iy1 < 64) ? wy1 * ms : 0.f;
        int cy0 = min(max(iy0, 0), 63), cy1 = min(max(iy1, 0), 63);
        float xa, xb; int q;
        if (ix0 >= 0 && ix0 <= 62)      { q = ix0; xa = 1.f - wx1; xb = wx1;       }
        else if (ix0 == -1)             { q = 0;   xa = wx1;       xb = 0.f;       }
        else if (ix0 == 63)             { q = 62;  xa = 0.f;       xb = 1.f - wx1; }
        else                            { q = 0;   xa = 0.f;       xb = 0.f;       }
        swL[e * 4 + 0] = wy0v * xa;
        swL[e * 4 + 1] = wy0v * xb;
        swL[e * 4 + 2] = wy1v * xa;
        swL[e * 4 + 3] = wy1v * xb;
        siL[e * 2 + 0] = (cy0 << 6) + q;
        siL[e * 2 + 1] = (cy1 << 6) + q;
    }

    floatx4 acc[2][2];
#pragma unroll
    for (int i = 0; i < 2; i++)
#pragma unroll
        for (int j = 0; j < 2; j++) acc[i][j] = (floatx4){0.f, 0.f, 0.f, 0.f};

    const int bp = tid & 31;           // pixel within tile
    const int cq = tid >> 5;           // 0..15, 2 channels each
    const int so = tid >> 1;           // A-stage row 0..255
    const int sh = tid & 1;            // A-stage half
    const size_t chbase = ((size_t)b * CB) << 12;

    __syncthreads();   // tables ready

    const int mbase = wid * 32;

    for (int cc = 0; cc < 8; cc++) {
        const int c0 = cc * 32;
        for (int tap = 0; tap < 9; tap++) {
            // A stage: w2bf[o][tap*256 + c0 .. c0+32)
            const unsigned short* gsrc =
                w2bf + (size_t)so * 2304 + tap * 256 + c0 + sh * 16;
            float4 v0 = *(const float4*)gsrc;
            float4 v1 = *(const float4*)(gsrc + 8);
            // B build: 2 channels for pixel bp, 1 aligned dword per (ch,row)
            floatx4 wv = *(const floatx4*)&swL[(tap * 32 + bp) * 4];
            int i0 = siL[(tap * 32 + bp) * 2 + 0];
            int i1 = siL[(tap * 32 + bp) * 2 + 1];
            const unsigned short* bs0 = (i0 & 1) ? bfB : bfA;
            unsigned short bvv[2];
#pragma unroll
            for (int s = 0; s < 2; s++) {
                size_t co = chbase + ((size_t)(c0 + cq * 2 + s) << 12);
                unsigned int d0 = *(const unsigned int*)(bs0 + co + (i0 & ~1));
                unsigned int d1 = *(const unsigned int*)(bs0 + co + (i1 & ~1));
                float acv = wv[0] * __uint_as_float(d0 << 16)
                          + wv[1] * __uint_as_float(d0 & 0xffff0000u)
                          + wv[2] * __uint_as_float(d1 << 16)
                          + wv[3] * __uint_as_float(d1 & 0xffff0000u);
                bvv[s] = f2bf(acv);
            }
            *(float4*)((char*)As + so * 80 + sh * 32) = v0;
            *(float4*)((char*)As + so * 80 + sh * 32 + 16) = v1;
            *(ushort2*)((char*)Bs + bp * 80 + cq * 4) = make_ushort2(bvv[0], bvv[1]);
            __syncthreads();
            shortx8 af[2], bfr[2];
#pragma unroll
            for (int i = 0; i < 2; i++)
                af[i] = *(const shortx8*)((const char*)As +
                        (mbase + 16 * i + l15) * 80 + quad * 16);
#pragma unroll
            for (int j = 0; j < 2; j++)
                bfr[j] = *(const shortx8*)((const char*)Bs +
                        (16 * j + l15) * 80 + quad * 16);
#pragma unroll
            for (int i = 0; i < 2; i++)
#pragma unroll
                for (int j = 0; j < 2; j++)
                    acc[i][j] = __builtin_amdgcn_mfma_f32_16x16x32_bf16(
                        af[i], bfr[j], acc[i][j], 0, 0, 0);
            __syncthreads();
        }
    }

    // epilogue: D col = lane&15, row = quad*4+reg
#pragma unroll
    for (int i = 0; i < 2; i++) {
#pragma unroll
        for (int r = 0; r < 4; r++) {
            int row = mbase + 16 * i + quad * 4 + r;
            float* dst = out2 + chbase + ((size_t)row << 12) + p0 + l15;
#pragma unroll
            for (int j = 0; j < 2; j++)
                dst[16 * j] = acc[i][j][r];
        }
    }
}

// ---------------------------------------------------------------------------
// Final: relu(gn3(d_out)*sc+bi + x) in place.
// ---------------------------------------------------------------------------
__global__ __launch_bounds__(256)
void final_k(float* __restrict__ dout, const float* __restrict__ x,
             const float2* __restrict__ stats, const float* __restrict__ sc,
             const float* __restrict__ bi) {
    long i = (long)blockIdx.x * 256 + threadIdx.x;
    long total4 = ((long)BATCH * CIN * PP) >> 2;
    if (i >= total4) return;
    long e = i << 2;
    int c = (int)((e >> 12) & 1023);
    int b = (int)(e >> 22);
    float2 st = stats[b * 32 + (c >> 5)];
    float a = st.y * sc[c];
    float bb = bi[c] - st.x * a;
    float4 v = ((float4*)dout)[i];
    float4 xv = ((const float4*)x)[i];
    v.x = fmaxf(v.x * a + bb + xv.x, 0.f);
    v.y = fmaxf(v.y * a + bb + xv.y, 0.f);
    v.z = fmaxf(v.z * a + bb + xv.z, 0.f);
    v.w = fmaxf(v.w * a + bb + xv.w, 0.f);
    ((float4*)dout)[i] = v;
}

// ---------------------------------------------------------------------------
// Workspace layout identical to R7/R8/R9 (50.9 MB, verified).
// ---------------------------------------------------------------------------
extern "C" void kernel_launch(void* const* d_in, const int* in_sizes, int n_in,
                              void* d_out, int out_size, void* d_ws, size_t ws_size,
                              hipStream_t stream) {
    const float* x   = (const float*)d_in[0];
    const float* w1  = (const float*)d_in[1];
    const float* g1s = (const float*)d_in[2];
    const float* g1b = (const float*)d_in[3];
    const float* wof = (const float*)d_in[4];
    const float* bof = (const float*)d_in[5];
    const float* w2  = (const float*)d_in[6];
    const float* g2s = (const float*)d_in[7];
    const float* g2b = (const float*)d_in[8];
    const float* w3  = (const float*)d_in[9];
    const float* g3s = (const float*)d_in[10];
    const float* g3b = (const float*)d_in[11];
    float* out = (float*)d_out;

    float* ws = (float*)d_ws;
    unsigned short* w1bf   = (unsigned short*)(ws + 0);
    float*          out1r  = ws + 131072;               // conv1 raw out
    float*          out2   = ws + 131072;               // aliases out1r (dead)
    unsigned short* xbfT   = (unsigned short*)(ws + 4325376);
    unsigned short* bfA    = (unsigned short*)(ws + 4325376);
    unsigned short* bfB    = (unsigned short*)(ws + 6422528);
    float*          om     = ws + 8519680;
    unsigned short* w2bf   = (unsigned short*)(ws + 8962048);
    unsigned short* out2bT = (unsigned short*)(ws + 4325376); // aliases bfA (dead)
    unsigned short* w3bf   = (unsigned short*)(ws + 11354112);
    float2* st1 = (float2*)(ws + 11485184);
    float2* st2 = st1 + 128;
    float2* st3 = st2 + 128;

    // x [b][1024][4096] -> xbfT [b][4096][1024] bf16
    transp_bf16<<<dim3(64, 16, 4), 256, 0, stream>>>(x, xbfT, 1024, 4096);
    cvt_bf16<<<1024, 256, 0, stream>>>(w1, w1bf, 262144);
    // conv1: out1r[b][256][4096] = w1bf @ xbfT   (xbfT dead after this)
    gemm_bf16<<<dim3(32, 2, 4), 256, 0, stream>>>(w1bf, xbfT, out1r, 256, 4096, 1024);
    gn_stats<<<128, 256, 0, stream>>>(out1r, st1, 256, 8);
    // GN1 apply -> bf16 bfA; shifted copy bfB
    gn1_apply_bf<<<4096, 256, 0, stream>>>(out1r, st1, g1s, g1b, bfA);
    mk_shift<<<16384, 256, 0, stream>>>(bfA, bfB);
    // offset conv (reads bfA)
    om_init<<<1728, 256, 0, stream>>>(om, bof);
    conv_off_k<<<dim3(16, 8, 4), 256, 0, stream>>>(bfA, wof, om);
    // weight conversions
    w2conv<<<2304, 256, 0, stream>>>(w2, w2bf);
    cvt_bf16<<<1024, 256, 0, stream>>>(w3, w3bf, 262144);
    // deformable einsum -> out2; 512 linear blocks, XCD<->batch swizzle
    gemm2_mfma<<<dim3(512, 1, 1), 512, 0, stream>>>(bfA, bfB, w2bf, om, out2);
    // GN2 stats + fused apply/relu/transpose -> out2bT (bfA region, now dead)
    gn_stats<<<128, 256, 0, stream>>>(out2, st2, 256, 8);
    gn2t<<<dim3(64, 4, 4), 256, 0, stream>>>(out2, st2, g2s, g2b, out2bT);
    // conv3: out[b][1024][4096] = w3bf @ out2bT
    gemm_bf16<<<dim3(32, 8, 4), 256, 0, stream>>>(w3bf, out2bT, out, 1024, 4096, 256);
    gn_stats<<<128, 256, 0, stream>>>(out, st3, 1024, 32);
    final_k<<<16384, 256, 0, stream>>>(out, x, st3, g3s, g3b);
}